// Round 19
// baseline (202.672 us; speedup 1.0000x reference)
//
#include <hip/hip_runtime.h>
#include <math.h>

#define NQ   11
#define DIM  2048        // 2^11
#define NL   6
#define SPB  4           // samples per block; grid = 8192/4 = 2048 (co-resident)

typedef float v2f __attribute__((ext_vector_type(2)));   // (re, im)

// h = g^{-1} of the CNOT-chain perm g(o)=o^(o>>1): prefix-XOR from MSB
__host__ __device__ constexpr int hperm(int x) {
    return x ^ (x>>1) ^ (x>>2) ^ (x>>3) ^ (x>>4) ^ (x>>5)
             ^ (x>>6) ^ (x>>7) ^ (x>>8) ^ (x>>9) ^ (x>>10);
}

// complex r = u*a + v*b
__device__ __forceinline__ v2f cfma2v(v2f u, v2f a, v2f v, v2f b) {
    v2f r;
    r.x = u.x*a.x - u.y*a.y + v.x*b.x - v.y*b.y;
    r.y = u.x*a.y + u.y*a.x + v.x*b.y + v.y*b.x;
    return r;
}

// DPP lane-xor (VALU pipe): 177=xor1, 78=xor2, 27=xor3, 0x128=row_ror:8(=xor8),
// 0x141=xor7, 0x140=xor15
template<int CTRL>
__device__ __forceinline__ v2f dpp_xor(v2f v) {
    const int x = __builtin_amdgcn_update_dpp(
        0, __float_as_int(v.x), CTRL, 0xF, 0xF, true);
    const int y = __builtin_amdgcn_update_dpp(
        0, __float_as_int(v.y), CTRL, 0xF, 0xF, true);
    v2f r; r.x = __int_as_float(x); r.y = __int_as_float(y);
    return r;
}
// lane-xor4 via ds_swizzle (no DPP encoding for xor4)
__device__ __forceinline__ v2f swz_xor4(v2f v) {
    v2f r;
    r.x = __int_as_float(__builtin_amdgcn_ds_swizzle(__float_as_int(v.x), 0x101F));
    r.y = __int_as_float(__builtin_amdgcn_ds_swizzle(__float_as_int(v.y), 0x101F));
    return r;
}

// ====== fused single kernel: redundant producer + SPB samples per block ======
// Producer (R16/R17-proven) runs in EVERY block -> no inter-block sync at all.
// Master S5 kept in registers m[16]; only one 16 KB LDS exchange buffer.
__global__ __launch_bounds__(128, 4) void qnn_all(
    const float* __restrict__ X,      // (B, NQ)
    const float* __restrict__ P,      // (NL, NQ, 3)
    float4* __restrict__ out4,        // (B, 1024) cells
    const int B)
{
    __shared__ float4 ldsc[DIM/2];    // exchange scratch, 16 KB
    __shared__ v2f   G[NL*NQ][4];     // fused shared-gate table, 2.1 KB
    __shared__ float2 gcs[SPB][NQ];   // per-sample sincos, 0.35 KB
    const int t  = threadIdx.x;       // 7 bits
    const int b0 = blockIdx.x * SPB;

    // ---- sincos for this block's SPB samples (44 values over 128 threads) ---
    if (t < SPB*NQ) {
        const int si = t / NQ, q = t - si*NQ;
        const float tx = 0.5f * X[(size_t)(b0+si)*NQ + q];
        gcs[si][q] = make_float2(cosf(tx), sinf(tx));
    }

    // ================= producer (R16/R17-proven) ==============================
    if (t < NL*NQ) {
        const float p0 = P[t*3+0], p1 = P[t*3+1], p2 = P[t*3+2];
        const float th = 0.5f*p1;
        const float c  = cosf(th), s = sinf(th);
        const float al = 0.5f*(p0+p2), be = 0.5f*(p0-p2);
        const float ca = cosf(al), sa = sinf(al);
        const float cb = cosf(be), sb = sinf(be);
        G[t][0] = (v2f){ c*ca, -c*sa};
        G[t][1] = (v2f){-s*cb, -s*sb};
        G[t][2] = (v2f){ s*cb, -s*sb};
        G[t][3] = (v2f){ c*ca,  c*sa};
    }
    // L0: a[2k+e] = amp (k<<8)|(t<<1)|e  (j=2k+e: amp10..8 = j3..1, amp0 = j0)
    v2f a[16];
    #pragma unroll
    for (int j = 0; j < 16; ++j) a[j] = (v2f){0.f, 0.f};
    if (t == 0) a[0] = (v2f){1.f, 0.f};
    __syncthreads();   // G + gcs ready

    const int cR = ((t>>4)<<7) | (t & 15);

    #define CGc(g_, m_) { \
        const v2f U00=G[g_][0], U01=G[g_][1], U10=G[g_][2], U11=G[g_][3]; \
        _Pragma("unroll") \
        for (int j = 0; j < 16; ++j) if (!(j & (m_))) { \
            const v2f x0 = a[j], x1 = a[j|(m_)]; \
            a[j]      = cfma2v(U00, x0, U01, x1); \
            a[j|(m_)] = cfma2v(U10, x0, U11, x1); \
        } }
    #define CGDc(g_, CTRL_, r_) { \
        const v2f Ca = (r_) ? G[g_][3] : G[g_][0]; \
        const v2f Cb = (r_) ? G[g_][2] : G[g_][1]; \
        _Pragma("unroll") \
        for (int k = 0; k < 8; ++k) { \
            const v2f o0 = a[2*k], o1 = a[2*k+1]; \
            const v2f p0 = dpp_xor<CTRL_>(o1); \
            const v2f p1 = dpp_xor<CTRL_>(o0); \
            a[2*k]   = cfma2v(Ca, o0, Cb, p0); \
            a[2*k+1] = cfma2v(Ca, o1, Cb, p1); \
        } }
    #define SGLc(g_, r_, FETCH) { \
        const v2f Ca = (r_) ? G[g_][3] : G[g_][0]; \
        const v2f Cb = (r_) ? G[g_][2] : G[g_][1]; \
        _Pragma("unroll") \
        for (int j = 0; j < 16; ++j) { \
            const v2f p = FETCH(a[j]); \
            a[j] = cfma2v(Ca, a[j], Cb, p); \
        } }

    v2f m[16];   // master S5, natural L0 register layout

    for (int l = 0; l < NL; ++l) {
        const int g0 = l*NQ;
        CGc(g0+0, 8) CGc(g0+1, 4) CGc(g0+2, 2) CGc(g0+10, 1)

        #pragma unroll
        for (int k = 0; k < 8; ++k)
            ldsc[(k<<7) | t] = make_float4(a[2*k].x, a[2*k].y, a[2*k+1].x, a[2*k+1].y);
        __syncthreads();
        #pragma unroll
        for (int k = 0; k < 8; ++k) {
            const float4 v = ldsc[cR | (k<<4)];
            a[2*k] = (v2f){v.x, v.y}; a[2*k+1] = (v2f){v.z, v.w};
        }
        CGc(g0+3, 8) CGc(g0+4, 4) CGc(g0+5, 2)

        if (l < NL-1) {
            __syncthreads();   // X1 reads done before h-scattered writes
            const int sB    = (((t>>4)&7)<<8) | (((t>>1)&7)<<2) | ((t&1)<<1);
            const int cellB = hperm(sB) >> 1;
            const int pt    = __popc(t) & 1;
            #pragma unroll
            for (int k = 0; k < 8; ++k) {
                const int cell = cellB ^ (hperm(k<<5) >> 1);
                const bool sw  = (pt ^ (__popc(k) & 1)) != 0;
                const v2f lo = sw ? a[2*k+1] : a[2*k];
                const v2f hi = sw ? a[2*k]   : a[2*k+1];
                ldsc[cell] = make_float4(lo.x, lo.y, hi.x, hi.y);
            }
            __syncthreads();
            #pragma unroll
            for (int k = 0; k < 8; ++k) {
                const float4 v = ldsc[(k<<7) | t];
                a[2*k] = (v2f){v.x, v.y}; a[2*k+1] = (v2f){v.z, v.w};
            }
            CGDc(g0+6, 0x140, ((t>>3) ^ (t>>4)) & 1)
            CGDc(g0+7, 0x141, ((t>>2) ^ (t>>3)) & 1)
            CGDc(g0+8, 27,    ((t>>1) ^ (t>>2)) & 1)
            CGDc(g0+9, 177,   ( t     ^ (t>>1)) & 1)
        } else {
            // layer 5, no perm. L1: amp bits 4..1 = t3..t0 -> plain lane gates
            SGLc(g0+6, (t>>3)&1, dpp_xor<0x128>)   // xor8
            SGLc(g0+7, (t>>2)&1, swz_xor4)         // xor4
            SGLc(g0+8, (t>>1)&1, dpp_xor<78>)      // xor2
            SGLc(g0+9,  t     &1, dpp_xor<177>)    // xor1
            // return to natural L0 REGISTER layout (X1 pattern, roles swapped)
            __syncthreads();   // prior perm-fold reads done (l=4 branch)
            #pragma unroll
            for (int k = 0; k < 8; ++k)
                ldsc[cR | (k<<4)] = make_float4(a[2*k].x, a[2*k].y,
                                                a[2*k+1].x, a[2*k+1].y);
            __syncthreads();
            #pragma unroll
            for (int k = 0; k < 8; ++k) {
                const float4 v = ldsc[(k<<7) | t];
                m[2*k] = (v2f){v.x, v.y}; m[2*k+1] = (v2f){v.z, v.w};
            }
            __syncthreads();   // m reads done before consumer overwrites ldsc
        }
    }
    #undef CGc
    #undef CGDc
    #undef SGLc

    // ================= consumer loop (R10-proven body), SPB samples ==========
    #define RG(q_, rb_) { \
        const float c = gcs[s][q_].x, sn = gcs[s][q_].y; \
        const v2f cc = {c, c}, sv = {sn, sn}; \
        _Pragma("unroll") \
        for (int j = 0; j < 16; ++j) if (!(j & (rb_))) { \
            const v2f a0 = a[j], a1 = a[j|(rb_)]; \
            a[j]       = cc*a0 - sv*a1; \
            a[j|(rb_)] = sv*a0 + cc*a1; \
        } }
    #define CGD(q_, CTRL_, r_) { \
        const float c = gcs[s][q_].x, sn = gcs[s][q_].y; \
        const float sg = (r_) ? sn : -sn; \
        const v2f cc = {c, c}, sgv = {sg, sg}; \
        _Pragma("unroll") \
        for (int k = 0; k < 8; ++k) { \
            const v2f o0 = a[2*k], o1 = a[2*k+1]; \
            const v2f p0 = dpp_xor<CTRL_>(o1); \
            const v2f p1 = dpp_xor<CTRL_>(o0); \
            a[2*k]   = cc*o0 + sgv*p0; \
            a[2*k+1] = cc*o1 + sgv*p1; \
        } }

    for (int s = 0; s < SPB; ++s) {
        if (b0 + s >= B) break;   // uniform per block

        #pragma unroll
        for (int j = 0; j < 16; ++j) a[j] = m[j];   // master -> working regs

        RG(0, 8) RG(1, 4) RG(2, 2) RG(10, 1)

        #pragma unroll
        for (int k = 0; k < 8; ++k)
            ldsc[(k<<7) | t] = make_float4(a[2*k].x, a[2*k].y, a[2*k+1].x, a[2*k+1].y);
        __syncthreads();
        #pragma unroll
        for (int k = 0; k < 8; ++k) {
            const float4 v = ldsc[cR | (k<<4)];
            a[2*k] = (v2f){v.x, v.y}; a[2*k+1] = (v2f){v.z, v.w};
        }
        RG(3, 8) RG(4, 4) RG(5, 2)
        __syncthreads();

        {
            const int sB    = (((t>>4)&7)<<8) | (((t>>1)&7)<<2) | ((t&1)<<1);
            const int cellB = hperm(sB) >> 1;
            const int pt    = __popc(t) & 1;
            #pragma unroll
            for (int k = 0; k < 8; ++k) {
                const int cell = cellB ^ (hperm(k<<5) >> 1);
                const bool sw  = (pt ^ (__popc(k) & 1)) != 0;
                const v2f lo = sw ? a[2*k+1] : a[2*k];
                const v2f hi = sw ? a[2*k]   : a[2*k+1];
                ldsc[cell] = make_float4(lo.x, lo.y, hi.x, hi.y);
            }
        }
        __syncthreads();

        #pragma unroll
        for (int k = 0; k < 8; ++k) {
            const float4 v = ldsc[(k<<7) | t];
            a[2*k] = (v2f){v.x, v.y}; a[2*k+1] = (v2f){v.z, v.w};
        }
        CGD(6, 0x140, ((t>>3) ^ (t>>4)) & 1)
        CGD(7, 0x141, ((t>>2) ^ (t>>3)) & 1)
        CGD(8, 27,    ((t>>1) ^ (t>>2)) & 1)
        CGD(9, 177,   ( t     ^ (t>>1)) & 1)

        float4* o = out4 + (size_t)(b0 + s) * (DIM/2);
        #pragma unroll
        for (int k = 0; k < 8; ++k)
            o[(k<<7) | t] = make_float4(a[2*k].x, a[2*k].y, a[2*k+1].x, a[2*k+1].y);

        __syncthreads();   // ldsc reuse guard before next sample's X1 write
    }
    #undef RG
    #undef CGD
}

extern "C" void kernel_launch(void* const* d_in, const int* in_sizes, int n_in,
                              void* d_out, int out_size, void* d_ws, size_t ws_size,
                              hipStream_t stream) {
    const float* X = (const float*)d_in[0];   // (B, NQ) float32
    const float* P = (const float*)d_in[1];   // (NL, NQ, 3) float32
    const int B = in_sizes[0] / NQ;           // 8192
    const int nb = (B + SPB - 1) / SPB;       // 2048 blocks
    qnn_all<<<nb, 128, 0, stream>>>(X, P, (float4*)d_out, B);
}

// Round 20
// 133.612 us; speedup vs baseline: 1.5169x; 1.5169x over previous
//
#include <hip/hip_runtime.h>
#include <math.h>

#define NQ   11
#define DIM  2048        // 2^11
#define NL   6
#define SPB  4           // samples per block; grid = 8192/4 = 2048 (co-resident)

typedef float v2f __attribute__((ext_vector_type(2)));   // (re, im)

// h = g^{-1} of the CNOT-chain perm g(o)=o^(o>>1): prefix-XOR from MSB
__host__ __device__ constexpr int hperm(int x) {
    return x ^ (x>>1) ^ (x>>2) ^ (x>>3) ^ (x>>4) ^ (x>>5)
             ^ (x>>6) ^ (x>>7) ^ (x>>8) ^ (x>>9) ^ (x>>10);
}

// complex r = u*a + v*b
__device__ __forceinline__ v2f cfma2v(v2f u, v2f a, v2f v, v2f b) {
    v2f r;
    r.x = u.x*a.x - u.y*a.y + v.x*b.x - v.y*b.y;
    r.y = u.x*a.y + u.y*a.x + v.x*b.y + v.y*b.x;
    return r;
}

// DPP lane-xor (VALU pipe): 177=xor1, 78=xor2, 27=xor3, 0x128=row_ror:8(=xor8),
// 0x141=xor7, 0x140=xor15
template<int CTRL>
__device__ __forceinline__ v2f dpp_xor(v2f v) {
    const int x = __builtin_amdgcn_update_dpp(
        0, __float_as_int(v.x), CTRL, 0xF, 0xF, true);
    const int y = __builtin_amdgcn_update_dpp(
        0, __float_as_int(v.y), CTRL, 0xF, 0xF, true);
    v2f r; r.x = __int_as_float(x); r.y = __int_as_float(y);
    return r;
}
// lane-xor4 via ds_swizzle (no DPP encoding for xor4)
__device__ __forceinline__ v2f swz_xor4(v2f v) {
    v2f r;
    r.x = __int_as_float(__builtin_amdgcn_ds_swizzle(__float_as_int(v.x), 0x101F));
    r.y = __int_as_float(__builtin_amdgcn_ds_swizzle(__float_as_int(v.y), 0x101F));
    return r;
}

// ====== fused single kernel: redundant producer + SPB samples per block ======
// R19 structure, but __launch_bounds__(128,2): 256-VGPR cap so the master
// state m[16] stays in REGISTERS (R19 spilled at the 64-VGPR pin: 302 MB
// scratch FETCH). Expected VGPR ~100-130 -> 4 waves/SIMD, no spill.
__global__ __launch_bounds__(128, 2) void qnn_all(
    const float* __restrict__ X,      // (B, NQ)
    const float* __restrict__ P,      // (NL, NQ, 3)
    float4* __restrict__ out4,        // (B, 1024) cells
    const int B)
{
    __shared__ float4 ldsc[DIM/2];    // exchange scratch, 16 KB
    __shared__ v2f   G[NL*NQ][4];     // fused shared-gate table, 2.1 KB
    __shared__ float2 gcs[SPB][NQ];   // per-sample sincos, 0.35 KB
    const int t  = threadIdx.x;       // 7 bits
    const int b0 = blockIdx.x * SPB;

    // ---- sincos for this block's SPB samples (44 values over 128 threads) ---
    if (t < SPB*NQ) {
        const int si = t / NQ, q = t - si*NQ;
        const float tx = 0.5f * X[(size_t)(b0+si)*NQ + q];
        gcs[si][q] = make_float2(cosf(tx), sinf(tx));
    }

    // ================= producer (R16/R17-proven) ==============================
    if (t < NL*NQ) {
        const float p0 = P[t*3+0], p1 = P[t*3+1], p2 = P[t*3+2];
        const float th = 0.5f*p1;
        const float c  = cosf(th), s = sinf(th);
        const float al = 0.5f*(p0+p2), be = 0.5f*(p0-p2);
        const float ca = cosf(al), sa = sinf(al);
        const float cb = cosf(be), sb = sinf(be);
        G[t][0] = (v2f){ c*ca, -c*sa};
        G[t][1] = (v2f){-s*cb, -s*sb};
        G[t][2] = (v2f){ s*cb, -s*sb};
        G[t][3] = (v2f){ c*ca,  c*sa};
    }
    // L0: a[2k+e] = amp (k<<8)|(t<<1)|e  (j=2k+e: amp10..8 = j3..1, amp0 = j0)
    v2f a[16];
    #pragma unroll
    for (int j = 0; j < 16; ++j) a[j] = (v2f){0.f, 0.f};
    if (t == 0) a[0] = (v2f){1.f, 0.f};
    __syncthreads();   // G + gcs ready

    const int cR = ((t>>4)<<7) | (t & 15);

    #define CGc(g_, m_) { \
        const v2f U00=G[g_][0], U01=G[g_][1], U10=G[g_][2], U11=G[g_][3]; \
        _Pragma("unroll") \
        for (int j = 0; j < 16; ++j) if (!(j & (m_))) { \
            const v2f x0 = a[j], x1 = a[j|(m_)]; \
            a[j]      = cfma2v(U00, x0, U01, x1); \
            a[j|(m_)] = cfma2v(U10, x0, U11, x1); \
        } }
    #define CGDc(g_, CTRL_, r_) { \
        const v2f Ca = (r_) ? G[g_][3] : G[g_][0]; \
        const v2f Cb = (r_) ? G[g_][2] : G[g_][1]; \
        _Pragma("unroll") \
        for (int k = 0; k < 8; ++k) { \
            const v2f o0 = a[2*k], o1 = a[2*k+1]; \
            const v2f p0 = dpp_xor<CTRL_>(o1); \
            const v2f p1 = dpp_xor<CTRL_>(o0); \
            a[2*k]   = cfma2v(Ca, o0, Cb, p0); \
            a[2*k+1] = cfma2v(Ca, o1, Cb, p1); \
        } }
    #define SGLc(g_, r_, FETCH) { \
        const v2f Ca = (r_) ? G[g_][3] : G[g_][0]; \
        const v2f Cb = (r_) ? G[g_][2] : G[g_][1]; \
        _Pragma("unroll") \
        for (int j = 0; j < 16; ++j) { \
            const v2f p = FETCH(a[j]); \
            a[j] = cfma2v(Ca, a[j], Cb, p); \
        } }

    v2f m[16];   // master S5, natural L0 register layout

    for (int l = 0; l < NL; ++l) {
        const int g0 = l*NQ;
        CGc(g0+0, 8) CGc(g0+1, 4) CGc(g0+2, 2) CGc(g0+10, 1)

        #pragma unroll
        for (int k = 0; k < 8; ++k)
            ldsc[(k<<7) | t] = make_float4(a[2*k].x, a[2*k].y, a[2*k+1].x, a[2*k+1].y);
        __syncthreads();
        #pragma unroll
        for (int k = 0; k < 8; ++k) {
            const float4 v = ldsc[cR | (k<<4)];
            a[2*k] = (v2f){v.x, v.y}; a[2*k+1] = (v2f){v.z, v.w};
        }
        CGc(g0+3, 8) CGc(g0+4, 4) CGc(g0+5, 2)

        if (l < NL-1) {
            __syncthreads();   // X1 reads done before h-scattered writes
            const int sB    = (((t>>4)&7)<<8) | (((t>>1)&7)<<2) | ((t&1)<<1);
            const int cellB = hperm(sB) >> 1;
            const int pt    = __popc(t) & 1;
            #pragma unroll
            for (int k = 0; k < 8; ++k) {
                const int cell = cellB ^ (hperm(k<<5) >> 1);
                const bool sw  = (pt ^ (__popc(k) & 1)) != 0;
                const v2f lo = sw ? a[2*k+1] : a[2*k];
                const v2f hi = sw ? a[2*k]   : a[2*k+1];
                ldsc[cell] = make_float4(lo.x, lo.y, hi.x, hi.y);
            }
            __syncthreads();
            #pragma unroll
            for (int k = 0; k < 8; ++k) {
                const float4 v = ldsc[(k<<7) | t];
                a[2*k] = (v2f){v.x, v.y}; a[2*k+1] = (v2f){v.z, v.w};
            }
            CGDc(g0+6, 0x140, ((t>>3) ^ (t>>4)) & 1)
            CGDc(g0+7, 0x141, ((t>>2) ^ (t>>3)) & 1)
            CGDc(g0+8, 27,    ((t>>1) ^ (t>>2)) & 1)
            CGDc(g0+9, 177,   ( t     ^ (t>>1)) & 1)
        } else {
            // layer 5, no perm. L1: amp bits 4..1 = t3..t0 -> plain lane gates
            SGLc(g0+6, (t>>3)&1, dpp_xor<0x128>)   // xor8
            SGLc(g0+7, (t>>2)&1, swz_xor4)         // xor4
            SGLc(g0+8, (t>>1)&1, dpp_xor<78>)      // xor2
            SGLc(g0+9,  t     &1, dpp_xor<177>)    // xor1
            // return to natural L0 REGISTER layout (X1 pattern, roles swapped)
            __syncthreads();   // prior perm-fold reads done (l=4 branch)
            #pragma unroll
            for (int k = 0; k < 8; ++k)
                ldsc[cR | (k<<4)] = make_float4(a[2*k].x, a[2*k].y,
                                                a[2*k+1].x, a[2*k+1].y);
            __syncthreads();
            #pragma unroll
            for (int k = 0; k < 8; ++k) {
                const float4 v = ldsc[(k<<7) | t];
                m[2*k] = (v2f){v.x, v.y}; m[2*k+1] = (v2f){v.z, v.w};
            }
            __syncthreads();   // m reads done before consumer overwrites ldsc
        }
    }
    #undef CGc
    #undef CGDc
    #undef SGLc

    // ================= consumer loop (R10-proven body), SPB samples ==========
    #define RG(q_, rb_) { \
        const float c = gcs[s][q_].x, sn = gcs[s][q_].y; \
        const v2f cc = {c, c}, sv = {sn, sn}; \
        _Pragma("unroll") \
        for (int j = 0; j < 16; ++j) if (!(j & (rb_))) { \
            const v2f a0 = a[j], a1 = a[j|(rb_)]; \
            a[j]       = cc*a0 - sv*a1; \
            a[j|(rb_)] = sv*a0 + cc*a1; \
        } }
    #define CGD(q_, CTRL_, r_) { \
        const float c = gcs[s][q_].x, sn = gcs[s][q_].y; \
        const float sg = (r_) ? sn : -sn; \
        const v2f cc = {c, c}, sgv = {sg, sg}; \
        _Pragma("unroll") \
        for (int k = 0; k < 8; ++k) { \
            const v2f o0 = a[2*k], o1 = a[2*k+1]; \
            const v2f p0 = dpp_xor<CTRL_>(o1); \
            const v2f p1 = dpp_xor<CTRL_>(o0); \
            a[2*k]   = cc*o0 + sgv*p0; \
            a[2*k+1] = cc*o1 + sgv*p1; \
        } }

    #pragma unroll
    for (int s = 0; s < SPB; ++s) {
        if (b0 + s >= B) break;   // uniform per block

        #pragma unroll
        for (int j = 0; j < 16; ++j) a[j] = m[j];   // master -> working regs

        RG(0, 8) RG(1, 4) RG(2, 2) RG(10, 1)

        #pragma unroll
        for (int k = 0; k < 8; ++k)
            ldsc[(k<<7) | t] = make_float4(a[2*k].x, a[2*k].y, a[2*k+1].x, a[2*k+1].y);
        __syncthreads();
        #pragma unroll
        for (int k = 0; k < 8; ++k) {
            const float4 v = ldsc[cR | (k<<4)];
            a[2*k] = (v2f){v.x, v.y}; a[2*k+1] = (v2f){v.z, v.w};
        }
        RG(3, 8) RG(4, 4) RG(5, 2)
        __syncthreads();

        {
            const int sB    = (((t>>4)&7)<<8) | (((t>>1)&7)<<2) | ((t&1)<<1);
            const int cellB = hperm(sB) >> 1;
            const int pt    = __popc(t) & 1;
            #pragma unroll
            for (int k = 0; k < 8; ++k) {
                const int cell = cellB ^ (hperm(k<<5) >> 1);
                const bool sw  = (pt ^ (__popc(k) & 1)) != 0;
                const v2f lo = sw ? a[2*k+1] : a[2*k];
                const v2f hi = sw ? a[2*k]   : a[2*k+1];
                ldsc[cell] = make_float4(lo.x, lo.y, hi.x, hi.y);
            }
        }
        __syncthreads();

        #pragma unroll
        for (int k = 0; k < 8; ++k) {
            const float4 v = ldsc[(k<<7) | t];
            a[2*k] = (v2f){v.x, v.y}; a[2*k+1] = (v2f){v.z, v.w};
        }
        CGD(6, 0x140, ((t>>3) ^ (t>>4)) & 1)
        CGD(7, 0x141, ((t>>2) ^ (t>>3)) & 1)
        CGD(8, 27,    ((t>>1) ^ (t>>2)) & 1)
        CGD(9, 177,   ( t     ^ (t>>1)) & 1)

        float4* o = out4 + (size_t)(b0 + s) * (DIM/2);
        #pragma unroll
        for (int k = 0; k < 8; ++k)
            o[(k<<7) | t] = make_float4(a[2*k].x, a[2*k].y, a[2*k+1].x, a[2*k+1].y);

        __syncthreads();   // ldsc reuse guard before next sample's X1 write
    }
    #undef RG
    #undef CGD
}

extern "C" void kernel_launch(void* const* d_in, const int* in_sizes, int n_in,
                              void* d_out, int out_size, void* d_ws, size_t ws_size,
                              hipStream_t stream) {
    const float* X = (const float*)d_in[0];   // (B, NQ) float32
    const float* P = (const float*)d_in[1];   // (NL, NQ, 3) float32
    const int B = in_sizes[0] / NQ;           // 8192
    const int nb = (B + SPB - 1) / SPB;       // 2048 blocks
    qnn_all<<<nb, 128, 0, stream>>>(X, P, (float4*)d_out, B);
}

// Round 22
// 49.789 us; speedup vs baseline: 4.0706x; 2.6836x over previous
//
#include <hip/hip_runtime.h>
#include <math.h>

#define NQ   11
#define DIM  2048        // 2^11
#define NL   6

typedef float v2f __attribute__((ext_vector_type(2)));   // (re, im)
typedef float v4f __attribute__((ext_vector_type(4)));   // native vec4 (nt-store ok)

// h = g^{-1} of the CNOT-chain perm g(o)=o^(o>>1): prefix-XOR from MSB
__host__ __device__ constexpr int hperm(int x) {
    return x ^ (x>>1) ^ (x>>2) ^ (x>>3) ^ (x>>4) ^ (x>>5)
             ^ (x>>6) ^ (x>>7) ^ (x>>8) ^ (x>>9) ^ (x>>10);
}

__device__ __forceinline__ float2 cfma2(float2 u, float2 a, float2 v, float2 b) {
    float2 r;
    r.x = u.x*a.x - u.y*a.y + v.x*b.x - v.y*b.y;
    r.y = u.x*a.y + u.y*a.x + v.x*b.y + v.y*b.x;
    return r;
}

// DPP lane-xor (VALU pipe): 177=xor1, 78=xor2, 27=xor3, 0x128=row_ror:8 (=xor8
// within 16-lane rows), 0x141=xor7, 0x140=xor15
template<int CTRL>
__device__ __forceinline__ v2f dpp_xor(v2f v) {
    const int x = __builtin_amdgcn_update_dpp(
        0, __float_as_int(v.x), CTRL, 0xF, 0xF, true);
    const int y = __builtin_amdgcn_update_dpp(
        0, __float_as_int(v.y), CTRL, 0xF, 0xF, true);
    v2f r; r.x = __int_as_float(x); r.y = __int_as_float(y);
    return r;
}
template<int CTRL>
__device__ __forceinline__ float2 dpp_xor_f2(float2 v) {
    float2 r;
    r.x = __int_as_float(__builtin_amdgcn_update_dpp(
        0, __float_as_int(v.x), CTRL, 0xF, 0xF, true));
    r.y = __int_as_float(__builtin_amdgcn_update_dpp(
        0, __float_as_int(v.y), CTRL, 0xF, 0xF, true));
    return r;
}

// p[lane] = v[lane^32] via v_permlane32_swap_b32 (VALU pipe, not LDS).
__device__ __forceinline__ float pl32_1(float v, bool hi) {
    int d0 = __float_as_int(v), d1 = d0;
    asm("v_permlane32_swap_b32 %0, %1" : "+v"(d0), "+v"(d1));
    return __int_as_float(hi ? d0 : d1);
}

// p[lane] = v[lane^m] (m=4 or 16) via ds_swizzle BitMode
#define SWZ4  0x101F
#define SWZ16 0x401F

// ============ kernel 1 v3: 1 block of 1024, VALU-pipe cross-lane gates =======
// (byte-for-byte the R15/R18-proven version)
__global__ __launch_bounds__(1024) void qnn_shared_kernel(
    const float* __restrict__ P,      // (NL, NQ, 3)
    float4* __restrict__ ws4)         // out: 1024 cells (amp pairs), natural
{
    __shared__ float2 lds[DIM];
    __shared__ float2 G[NL*NQ][4];
    const int t = threadIdx.x;        // 10 bits

    if (t < NL*NQ) {
        const float p0 = P[t*3+0], p1 = P[t*3+1], p2 = P[t*3+2];
        const float th = 0.5f*p1;
        const float c  = cosf(th), s = sinf(th);
        const float al = 0.5f*(p0+p2), be = 0.5f*(p0-p2);
        const float ca = cosf(al), sa = sinf(al);
        const float cb = cosf(be), sb = sinf(be);
        G[t][0] = make_float2( c*ca, -c*sa);
        G[t][1] = make_float2(-s*cb, -s*sb);
        G[t][2] = make_float2( s*cb, -s*sb);
        G[t][3] = make_float2( c*ca,  c*sa);
    }

    // swzC(a) = a ^ ((a>>6)&15)  (GF(2)-linear, bit10 untouched)
    const int b0 = t ^ ((t >> 6) & 15);                       // X1 write base
    const int lin1 = (((t>>2)&15)<<6) | (((t>>6)&15)<<2) | (t&3);
    const int b1 = lin1 ^ ((t >> 2) & 15);                    // X1 read / X2 write
    const int gt = t ^ (t >> 1);
    const int b2 = gt ^ ((gt >> 6) & 15);                     // X2 perm read (k=0)
    const int bn = (2*t) ^ (((2*t) >> 6) & 15);               // final natural read

    float2 a0 = make_float2(0.f, 0.f), a1 = make_float2(0.f, 0.f);
    if (t == 0) a0 = make_float2(1.f, 0.f);
    __syncthreads();   // G ready

    const bool hi32 = (t & 32) != 0;

    #define CGK(g_) { \
        const float2 n0 = cfma2(G[g_][0], a0, G[g_][1], a1); \
        const float2 n1 = cfma2(G[g_][2], a0, G[g_][3], a1); \
        a0 = n0; a1 = n1; }

    #define SGP(g_) { \
        const float2 ca_ = hi32 ? G[g_][3] : G[g_][0]; \
        const float2 cb_ = hi32 ? G[g_][2] : G[g_][1]; \
        float2 p; \
        p.x = pl32_1(a0.x, hi32); p.y = pl32_1(a0.y, hi32); \
        a0 = cfma2(ca_, a0, cb_, p); \
        p.x = pl32_1(a1.x, hi32); p.y = pl32_1(a1.y, hi32); \
        a1 = cfma2(ca_, a1, cb_, p); }

    #define SGS(g_, m_, OFF_) { \
        const int bb = (t & (m_)) ? 1 : 0; \
        const float2 ca_ = bb ? G[g_][3] : G[g_][0]; \
        const float2 cb_ = bb ? G[g_][2] : G[g_][1]; \
        float2 p; \
        p.x = __int_as_float(__builtin_amdgcn_ds_swizzle(__float_as_int(a0.x), OFF_)); \
        p.y = __int_as_float(__builtin_amdgcn_ds_swizzle(__float_as_int(a0.y), OFF_)); \
        a0 = cfma2(ca_, a0, cb_, p); \
        p.x = __int_as_float(__builtin_amdgcn_ds_swizzle(__float_as_int(a1.x), OFF_)); \
        p.y = __int_as_float(__builtin_amdgcn_ds_swizzle(__float_as_int(a1.y), OFF_)); \
        a1 = cfma2(ca_, a1, cb_, p); }

    #define SGD(g_, CTRL_, m_) { \
        const int bb = (t & (m_)) ? 1 : 0; \
        const float2 ca_ = bb ? G[g_][3] : G[g_][0]; \
        const float2 cb_ = bb ? G[g_][2] : G[g_][1]; \
        float2 p = dpp_xor_f2<CTRL_>(a0); \
        a0 = cfma2(ca_, a0, cb_, p); \
        p = dpp_xor_f2<CTRL_>(a1); \
        a1 = cfma2(ca_, a1, cb_, p); }

    for (int l = 0; l < NL; ++l) {
        const int g0 = l*NQ;
        // phase A (L0: amp=(k<<10)|t): q0 reg; q5..q10 on lane bits 5..0
        CGK(g0+0)
        SGP(g0+5)                                    // mask 32 (VALU)
        SGS(g0+6, 16, SWZ16)                         // mask 16 (LDS swizzle)
        SGD(g0+7, 0x128, 8)                          // mask 8  (DPP row_ror:8)
        SGS(g0+8, 4, SWZ4)                           // mask 4  (LDS swizzle)
        SGD(g0+9, 78, 2) SGD(g0+10, 177, 1)          // masks 2,1 (DPP)

        // X1 -> L1: amp[9:6]=t'[5:2], amp[5:2]=t'[9:6]
        lds[b0] = a0; lds[b0 ^ 1024] = a1;
        __syncthreads();
        a0 = lds[b1]; a1 = lds[b1 ^ 1024];

        // phase B: q1..q4 on amp bits 9..6 = lane bits 5..2
        SGP(g0+1)                                    // mask 32
        SGS(g0+2, 16, SWZ16)                         // mask 16
        SGD(g0+3, 0x128, 8)                          // mask 8
        SGS(g0+4, 4, SWZ4)                           // mask 4

        // X2 write: exact same per-thread slots as X1 read -> no pre-barrier
        lds[b1] = a0; lds[b1 ^ 1024] = a1;
        __syncthreads();
        if (l < NL-1) {
            // perm-fold read back to L0: a[k] = state[g((k<<10)|t)]
            a0 = lds[b2]; a1 = lds[b2 ^ 1544];
            __syncthreads();
        } else {
            // layer 5: no perm; natural-order cell write (amps 2t, 2t+1)
            const float2 lo = lds[bn], hi = lds[bn ^ 1];
            ws4[t] = make_float4(lo.x, lo.y, hi.x, hi.y);
        }
    }
    #undef CGK
    #undef SGP
    #undef SGS
    #undef SGD
}

// ========= kernel 2: cell-paired (float4) layout, 8192 blocks ================
// R10-proven body; output stores NON-TEMPORAL via native clang vec4 (write-once
// data streams to HBM without evicting the 8192-block-shared S5 L2 lines).
__global__ __launch_bounds__(128, 4) void qnn_last_kernel(
    const float* __restrict__ X,      // (B, NQ)
    const float4* __restrict__ S5c,   // shared state, 1024 cells, natural order
    float4* __restrict__ out4)        // (B, 1024) cells
{
    __shared__ float4 ldsc[DIM/2];    // 1024 cells = 16 KB
    __shared__ float2 gc[NQ];
    const int b = blockIdx.x;
    const int t = threadIdx.x;        // 7 bits

    if (t < NQ) {
        const float tx = 0.5f * X[(size_t)b*NQ + t];
        gc[t] = make_float2(cosf(tx), sinf(tx));
    }

    // L0: a[2k+e] = amp s=(k<<8)|(t<<1)|e ; cell (k<<7)|t ; 1KB/wave loads
    v2f a[16];
    #pragma unroll
    for (int k = 0; k < 8; ++k) {
        const float4 v = S5c[(k<<7) | t];
        a[2*k]   = (v2f){v.x, v.y};
        a[2*k+1] = (v2f){v.z, v.w};
    }
    __syncthreads();   // bar1: gc ready

    // packed real RY on a-index bit rb_
    #define RG(q_, rb_) { \
        const float c = gc[q_].x, sn = gc[q_].y; \
        const v2f cc = {c, c}, sv = {sn, sn}; \
        _Pragma("unroll") \
        for (int j = 0; j < 16; ++j) if (!(j & (rb_))) { \
            const v2f a0 = a[j], a1 = a[j|(rb_)]; \
            a[j]       = cc*a0 - sv*a1; \
            a[j|(rb_)] = sv*a0 + cc*a1; \
        } }

    // o-domain conjugated RY: partner = lane-xor (DPP) of e-swapped reg
    #define CGD(q_, CTRL_, r_) { \
        const float c = gc[q_].x, sn = gc[q_].y; \
        const float sg = (r_) ? sn : -sn; \
        const v2f cc = {c, c}, sgv = {sg, sg}; \
        _Pragma("unroll") \
        for (int k = 0; k < 8; ++k) { \
            const v2f o0 = a[2*k], o1 = a[2*k+1]; \
            const v2f p0 = dpp_xor<CTRL_>(o1); \
            const v2f p1 = dpp_xor<CTRL_>(o0); \
            a[2*k]   = cc*o0 + sgv*p0; \
            a[2*k+1] = cc*o1 + sgv*p1; \
        } }

    // S1: reg amp-bits {10,9,8} = k, {0} = e
    RG(0, 8) RG(1, 4) RG(2, 2) RG(10, 1)

    // X1 write: cell (k<<7)|t
    #pragma unroll
    for (int k = 0; k < 8; ++k)
        ldsc[(k<<7) | t] = make_float4(a[2*k].x, a[2*k].y, a[2*k+1].x, a[2*k+1].y);
    __syncthreads();   // bar2
    // X1 read: s = (t[6:4]<<8)|(k<<5)|(t[3:1]<<2)|(t0<<1)|e ; cell = s>>1
    const int cR = ((t>>4)<<7) | (t & 15);
    #pragma unroll
    for (int k = 0; k < 8; ++k) {
        const float4 v = ldsc[cR | (k<<4)];
        a[2*k]   = (v2f){v.x, v.y};
        a[2*k+1] = (v2f){v.z, v.w};
    }
    // S2: reg amp-bits {7,6,5} = k
    RG(3, 8) RG(4, 4) RG(5, 2)
    __syncthreads();   // bar3: all X1 reads done before h-scattered writes

    // X2 write, perm-folded: amp s -> LDS slot h(s), so LDS[o] = V[g(o)].
    {
        const int sB    = (((t>>4)&7)<<8) | (((t>>1)&7)<<2) | ((t&1)<<1);
        const int cellB = hperm(sB) >> 1;
        const int pt    = __popc(t) & 1;
        #pragma unroll
        for (int k = 0; k < 8; ++k) {
            const int cell = cellB ^ (hperm(k<<5) >> 1);   // constexpr k-part
            const bool sw  = (pt ^ (__popc(k) & 1)) != 0;
            const v2f lo = sw ? a[2*k+1] : a[2*k];
            const v2f hi = sw ? a[2*k]   : a[2*k+1];
            ldsc[cell] = make_float4(lo.x, lo.y, hi.x, hi.y);
        }
    }
    __syncthreads();   // bar4

    // X2 read, linear: a[2k+e] = V[g(o)], o = (k<<8)|(t<<1)|e
    #pragma unroll
    for (int k = 0; k < 8; ++k) {
        const float4 v = ldsc[(k<<7) | t];
        a[2*k]   = (v2f){v.x, v.y};
        a[2*k+1] = (v2f){v.z, v.w};
    }

    // S3: q6..q9 conjugated through g -> lane-xor {15,7,3,1} + e-swap
    CGD(6, 0x140, ((t>>3) ^ (t>>4)) & 1)
    CGD(7, 0x141, ((t>>2) ^ (t>>3)) & 1)
    CGD(8, 27,    ((t>>1) ^ (t>>2)) & 1)
    CGD(9, 177,   ( t     ^ (t>>1)) & 1)

    // store: cell (k<<7)|t -> 1KB/wave contiguous bursts, NON-TEMPORAL
    v4f* o = (v4f*)(out4 + (size_t)b * (DIM/2));
    #pragma unroll
    for (int k = 0; k < 8; ++k) {
        const v4f v = {a[2*k].x, a[2*k].y, a[2*k+1].x, a[2*k+1].y};
        __builtin_nontemporal_store(v, &o[(k<<7) | t]);
    }
    #undef RG
    #undef CGD
}

extern "C" void kernel_launch(void* const* d_in, const int* in_sizes, int n_in,
                              void* d_out, int out_size, void* d_ws, size_t ws_size,
                              hipStream_t stream) {
    const float* X = (const float*)d_in[0];   // (B, NQ) float32
    const float* P = (const float*)d_in[1];   // (NL, NQ, 3) float32
    float4* ws4 = (float4*)d_ws;              // 16 KB shared state, cell layout
    const int B = in_sizes[0] / NQ;           // 8192
    qnn_shared_kernel<<<1, 1024, 0, stream>>>(P, ws4);
    qnn_last_kernel<<<B, 128, 0, stream>>>(X, (const float4*)ws4, (float4*)d_out);
}